// Round 1
// 375.750 us; speedup vs baseline: 1.0196x; 1.0196x over previous
//
#include <hip/hip_runtime.h>

#define HW    4096
#define CKD   64
#define CVD   512
#define NBATCH 8
#define BQ    128
#define BM    64
#define NIT   64       // HW / BM
#define PSTR  72       // P-tile LDS row stride (bf16 elems): 144 B rows, 16B-aligned

typedef __attribute__((ext_vector_type(8))) short  short8;
typedef __attribute__((ext_vector_type(4))) float  floatx4;
typedef __attribute__((ext_vector_type(4))) int    intx4;
typedef __attribute__((ext_vector_type(2))) int    intx2;
typedef __attribute__((ext_vector_type(2))) float  floatx2;

static __device__ __forceinline__ unsigned short f2bf(float f) {
  unsigned u = __float_as_uint(f);
  u = (u + 0x7fffu + ((u >> 16) & 1u)) >> 16;   // RTNE
  return (unsigned short)u;
}
static __device__ __forceinline__ unsigned pack2(float a, float b) {
  return (unsigned)f2bf(a) | ((unsigned)f2bf(b) << 16);
}

// ---------------- pre-pass: f32 -> bf16 (RTNE), pairwise (mv) ----------------
__global__ __launch_bounds__(256) void cvt_bf16(const float* __restrict__ src,
                                                unsigned* __restrict__ dst, int n2) {
  int i = blockIdx.x * 256 + threadIdx.x;
  if (i < n2) {
    floatx2 f = ((const floatx2*)src)[i];
    dst[i] = pack2(f.x, f.y);
  }
}

// ---------------- pre-pass: f32 [CK][HW] -> bf16 [HW][CK] (transpose+convert) ----
// Thread owns one m-row: 64 coalesced f32 reads (per c, 256 consecutive lanes),
// writes one contiguous 128 B bf16 row. 16 blocks/batch.
__global__ __launch_bounds__(256) void cvtT_bf16(const float* __restrict__ src,
                                                 intx4* __restrict__ dst) {
  const int bb = blockIdx.x >> 4;                       // batch
  const int m  = ((blockIdx.x & 15) << 8) | threadIdx.x;
  const float* s = src + (size_t)bb * CKD * HW + m;
  intx4* d = dst + ((size_t)bb * HW + m) * (CKD * 2 / 16);   // 8 intx4 per row
  #pragma unroll
  for (int v = 0; v < 8; ++v) {
    intx4 o;
    #pragma unroll
    for (int k = 0; k < 4; ++k) {
      float f0 = s[(size_t)(v * 8 + 2 * k    ) * HW];
      float f1 = s[(size_t)(v * 8 + 2 * k + 1) * HW];
      o[k] = (int)pack2(f0, f1);
    }
    d[v] = o;
  }
}

// fragment loaders, templated on storage dtype (BF=true: bf16 in ws)
template<bool BF>
static __device__ __forceinline__ short8 ld8_strided(const char* p, int idx) {
  short8 f;
  if constexpr (BF) {
    const unsigned short* q = (const unsigned short*)p + idx;
    #pragma unroll
    for (int j = 0; j < 8; ++j) f[j] = (short)q[(size_t)j * HW];
  } else {
    const float* q = (const float*)p + idx;
    #pragma unroll
    for (int j = 0; j < 8; ++j) f[j] = (short)f2bf(q[(size_t)j * HW]);
  }
  return f;
}
template<bool BF>
static __device__ __forceinline__ short8 ld8_contig(const char* p, size_t idx) {
  if constexpr (BF) {
    union { intx4 i; short8 s; } u;
    u.i = *(const intx4*)((const unsigned short*)p + idx);
    return u.s;
  } else {
    const float* q = (const float*)p + idx;
    short8 f;
    #pragma unroll
    for (int j = 0; j < 4; ++j) {
      unsigned v = pack2(q[2*j], q[2*j+1]);
      f[2*j]   = (short)(v & 0xffffu);
      f[2*j+1] = (short)(v >> 16);
    }
    return f;
  }
}

// BF=true:  mk = mkT [HW][CK] bf16, qk = qkT [HW][CK] bf16, mv = [CV][HW] bf16
// BF=false: original f32 layouts ([CK][HW], [CK][HW], [CV][HW])
template<bool BF>
__global__ __launch_bounds__(512, 2) void attn_main(
    const void* __restrict__ Mkp, const void* __restrict__ Qkp,
    const void* __restrict__ Mvp, float* __restrict__ Out)
{
  __shared__ alignas(16) short Pt[2][BQ * PSTR];   // 36864 B
  __shared__ float lsum[BQ];

  const int bx   = blockIdx.x;
  const int b    = bx & 7;            // XCD-affine: batch b -> XCD b
  const int q0   = (bx >> 3) * BQ;
  const int tid  = threadIdx.x;
  const int w    = tid >> 6;          // wave 0..7
  const int lane = tid & 63;
  const int quad = lane >> 4;
  const int col  = lane & 15;

  const size_t esz = BF ? 2 : 4;
  const char* mk = (const char*)Mkp + (size_t)b * CKD * HW * esz;
  const char* qk = (const char*)Qkp + (size_t)b * CKD * HW * esz;
  const char* mv = (const char*)Mvp + (size_t)b * CVD * HW * esz;
  float*      out = Out + (size_t)b * CVD * HW;

  if (tid < BQ) lsum[tid] = 0.0f;

  // B-fragments of qk (fixed for whole block): wave w owns q-tile qhat=w.
  // B[k=c][n=q], c = ks*32 + quad*8 + j  -> contiguous in c with qkT layout
  short8 bq[2];
  #pragma unroll
  for (int ks = 0; ks < 2; ++ks) {
    if constexpr (BF)
      bq[ks] = ld8_contig<true>(qk, (size_t)(q0 + w*16 + col) * CKD + ks*32 + quad*8);
    else
      bq[ks] = ld8_strided<false>(qk, (ks*32 + quad*8) * HW + q0 + w*16 + col);
  }

  floatx4 acc[4][8];   // [ch][qh]: wave w owns cv rows [w*64, w*64+64), all 128 q
  #pragma unroll
  for (int i = 0; i < 4; ++i)
    #pragma unroll
    for (int j = 0; j < 8; ++j) acc[i][j] = (floatx4)0.0f;

  float lacc = 0.0f;
  const float SC = 0.18033688011112042f;   // (1/sqrt(64)) * log2(e)

  __syncthreads();

  for (int it = 0; it < NIT; ++it) {
    const int m0 = it * BM;
    short* Pb = &Pt[it & 1][0];

    // ---- prefetch mv fragments for GEMM2: issued before GEMM1 so L2 latency
    //      hides under GEMM1 compute (consumed only after the barrier)
    short8 av[4][2];
    #pragma unroll
    for (int ch = 0; ch < 4; ++ch)
      #pragma unroll
      for (int ks = 0; ks < 2; ++ks)
        av[ch][ks] = ld8_contig<BF>(mv, (size_t)(w*64 + ch*16 + col) * HW + m0 + ks*32 + quad*8);

    // ---- GEMM1: S[m][q], wave w does tiles (mh=0..3, qhat=w); exp -> P^T in LDS
    #pragma unroll
    for (int mh = 0; mh < 4; ++mh) {
      floatx4 s = (floatx4)0.0f;
      #pragma unroll
      for (int ks = 0; ks < 2; ++ks) {
        short8 a;
        if constexpr (BF)   // A[m=col][k=c] from mkT: one dwordx4, contiguous in c
          a = ld8_contig<true>(mk, (size_t)(m0 + mh*16 + col) * CKD + ks*32 + quad*8);
        else
          a = ld8_strided<false>(mk, (ks*32 + quad*8) * HW + m0 + mh*16 + col);
        s = __builtin_amdgcn_mfma_f32_16x16x32_bf16(a, bq[ks], s, 0, 0, 0);
      }
      // C layout: n=q=col, m = quad*4 + r
      const float p0 = exp2f(s[0] * SC);
      const float p1 = exp2f(s[1] * SC);
      const float p2 = exp2f(s[2] * SC);
      const float p3 = exp2f(s[3] * SC);
      lacc += (p0 + p1) + (p2 + p3);
      intx2 pv;
      pv[0] = (int)pack2(p0, p1);
      pv[1] = (int)pack2(p2, p3);
      *(intx2*)(Pb + (w*16 + col) * PSTR + mh*16 + quad*4) = pv;
    }
    __syncthreads();   // single barrier/iter; P double-buffered

    // ---- GEMM2: O[cv][q] += mv[cv][m] * P[m][q]
    #pragma unroll
    for (int qh = 0; qh < 8; ++qh) {
      union { intx4 i; short8 s; } u0, u1;
      u0.i = *(const intx4*)(Pb + (qh*16 + col) * PSTR + quad*8);
      u1.i = *(const intx4*)(Pb + (qh*16 + col) * PSTR + 32 + quad*8);
      #pragma unroll
      for (int ch = 0; ch < 4; ++ch) {
        acc[ch][qh] = __builtin_amdgcn_mfma_f32_16x16x32_bf16(av[ch][0], u0.s, acc[ch][qh], 0, 0, 0);
        acc[ch][qh] = __builtin_amdgcn_mfma_f32_16x16x32_bf16(av[ch][1], u1.s, acc[ch][qh], 0, 0, 0);
      }
    }
  }

  // ---- softmax denominators: 4 lanes (quads) contribute per q column
  atomicAdd(&lsum[w*16 + col], lacc);
  __syncthreads();

  float rl[8];
  #pragma unroll
  for (int qh = 0; qh < 8; ++qh) rl[qh] = 1.0f / lsum[qh*16 + col];

  // ---- epilogue: normalize + store f32
  #pragma unroll
  for (int ch = 0; ch < 4; ++ch) {
    #pragma unroll
    for (int r = 0; r < 4; ++r) {
      const int cv = w*64 + ch*16 + quad*4 + r;
      float* orow = out + (size_t)cv * HW + q0 + col;
      #pragma unroll
      for (int qh = 0; qh < 8; ++qh)
        orow[qh*16] = acc[ch][qh][r] * rl[qh];
    }
  }
}

extern "C" void kernel_launch(void* const* d_in, const int* in_sizes, int n_in,
                              void* d_out, int out_size, void* d_ws, size_t ws_size,
                              hipStream_t stream) {
  const float* Mk = (const float*)d_in[0];
  const float* Qk = (const float*)d_in[1];
  const float* Mv = (const float*)d_in[2];
  float* Out = (float*)d_out;
  (void)in_sizes; (void)n_in; (void)out_size;

  const size_t NMK = (size_t)NBATCH * CKD * HW;   // 2,097,152
  const size_t NMV = (size_t)NBATCH * CVD * HW;   // 16,777,216
  const size_t need = (2 * NMK + NMV) * 2;        // 41,943,040 B

  if (ws_size >= need) {
    unsigned short* mkw = (unsigned short*)d_ws;
    unsigned short* qkw = mkw + NMK;
    unsigned short* mvw = qkw + NMK;
    cvtT_bf16<<<NBATCH * (HW/256), 256, 0, stream>>>(Mk, (intx4*)mkw);
    cvtT_bf16<<<NBATCH * (HW/256), 256, 0, stream>>>(Qk, (intx4*)qkw);
    cvt_bf16<<<(int)(NMV/2/256), 256, 0, stream>>>(Mv, (unsigned*)mvw, (int)(NMV/2));
    attn_main<true><<<NBATCH * (HW/BQ), 512, 0, stream>>>(mkw, qkw, mvw, Out);
  } else {
    attn_main<false><<<NBATCH * (HW/BQ), 512, 0, stream>>>(Mk, Qk, Mv, Out);
  }
}